// Round 5
// baseline (2500.114 us; speedup 1.0000x reference)
//
#include <hip/hip_runtime.h>

#define HH   100      // hidden
#define G4   400      // 4*H
#define BB   256      // batch
#define CC   9        // input channels
#define TT   1024     // timesteps
#define NCLS 6        // num classes
#define XSTR 13       // padded stride for transposed x tile

__device__ __forceinline__ float sigm(float x) {
    return __fdividef(1.0f, 1.0f + __expf(-x));
}
__device__ __forceinline__ float tanh_fast(float x) {
    return 2.0f * sigm(2.0f * x) - 1.0f;
}
// wave-wide broadcast of lane l's value via readlane -> SGPR (no LDS pipe).
// REQUIRES: v computed by ALL 64 lanes of the wave (no divergence upstream).
__device__ __forceinline__ float bcast(float v, int l) {
    return __int_as_float(__builtin_amdgcn_readlane(__float_as_int(v), l));
}

// ---------------- Layer 1: x[B,C,T] -> h1[B,T,H] ----------------
// 896 threads: waves 0-6 = half0 (x-dot + w_hh[0:46]), waves 7-13 = half1
// (w_hh[46:100]). Each thread holds <=56 weight floats -> no spill.
__global__ __launch_bounds__(896, 2)
void lstm_layer1(const float* __restrict__ x,     // [B,C,T]
                 const float* __restrict__ h0,    // [B,H]
                 const float* __restrict__ c0,    // [B,H]
                 const float* __restrict__ W_ih,  // [400,9]
                 const float* __restrict__ W_hh,  // [400,100]
                 const float* __restrict__ bias_g,// [400]
                 float* __restrict__ h1out)       // [B,T,H]
{
    const int b    = blockIdx.x;
    const int tid  = threadIdx.x;
    const int lane = tid & 63;

    __shared__ float xT[TT * XSTR + 64];   // transposed x: xT[t*13 + c]
    __shared__ float hb[128];              // h, padded + zeroed
    __shared__ float p[2][448];            // per-half partial sums

    const float* xb = x + (size_t)b * CC * TT;
    for (int i = tid; i < CC * TT; i += 896) {
        int c  = i >> 10;
        int tp = i & 1023;
        xT[tp * XSTR + c] = xb[i];
    }
    if (tid < 128) hb[tid] = (tid < HH) ? h0[b * HH + tid] : 0.0f;
    float c_reg = (tid < HH) ? c0[b * HH + tid] : 0.0f;

    const bool half0 = (tid < 448);
    const int  r     = half0 ? tid : (tid - 448);
    const int  row   = (r < G4) ? r : 0;

    // half0: w[0..8]=W_ih[row], w[9..54]=W_hh[row][0..45], +bias
    // half1: w[0..53]=W_hh[row][46..99]
    float w[55], bg = 0.0f;
    if (half0) {
        #pragma unroll
        for (int j = 0; j < CC; ++j) w[j] = W_ih[row * CC + j];
        #pragma unroll
        for (int j = 0; j < 46; ++j) w[CC + j] = W_hh[row * HH + j];
        bg = bias_g[row];
    } else {
        #pragma unroll
        for (int j = 0; j < 54; ++j) w[j] = W_hh[row * HH + 46 + j];
        w[54] = 0.0f;
    }
    #pragma unroll
    for (int j = 0; j < 55; ++j) asm volatile("" : "+v"(w[j]));  // no remat

    float* hout = h1out + (size_t)b * TT * HH;
    __syncthreads();

    for (int t = 0; t < TT; ++t) {
        if (half0) {
            float vx = xT[t * XSTR + lane];
            float va = hb[lane];
            asm volatile("" : "+v"(vx), "+v"(va));
            float a0 = bg, a1 = 0.f;
            #pragma unroll
            for (int c = 0; c < CC; ++c) {
                float h_ = bcast(vx, c);
                if (c & 1) a1 += h_ * w[c]; else a0 += h_ * w[c];
            }
            #pragma unroll
            for (int j = 0; j < 46; ++j) {
                float h_ = bcast(va, j);
                if (j & 1) a1 += h_ * w[CC + j]; else a0 += h_ * w[CC + j];
            }
            p[0][tid] = a0 + a1;
        } else {
            float vb = hb[46 + lane];   // lanes 0..53 -> h[46..99]; rest pad(0)
            asm volatile("" : "+v"(vb));
            float a0 = 0.f, a1 = 0.f;
            #pragma unroll
            for (int j = 0; j < 54; ++j) {
                float h_ = bcast(vb, j);
                if (j & 1) a1 += h_ * w[j]; else a0 += h_ * w[j];
            }
            p[1][tid - 448] = a0 + a1;
        }
        __syncthreads();
        if (tid < HH) {
            float ri = p[0][tid]          + p[1][tid];
            float rf = p[0][tid + HH]     + p[1][tid + HH];
            float rg = p[0][tid + 2 * HH] + p[1][tid + 2 * HH];
            float ro = p[0][tid + 3 * HH] + p[1][tid + 3 * HH];
            float cc = sigm(rf) * c_reg + sigm(ri) * tanh_fast(rg);
            c_reg = cc;
            float hv = sigm(ro) * tanh_fast(cc);
            hb[tid] = hv;
            hout[t * HH + tid] = hv;
        }
        __syncthreads();
    }
}

// -------- Layer 2 + final FC: h1[B,T,H] -> out[B,NC] --------
// 960 threads: waves 0-6 = half0 (W_ih . h1_t), waves 7-13 = half1
// (W_hh . h2_{t-1}), wave 14 = h1 prefetch. <=101 weight floats/thread.
__global__ __launch_bounds__(960, 2)
void lstm_layer2_fc(const float* __restrict__ h1,   // [B,T,H]
                    const float* __restrict__ h0,
                    const float* __restrict__ c0,
                    const float* __restrict__ W_ih, // [400,100]
                    const float* __restrict__ W_hh, // [400,100]
                    const float* __restrict__ bias_g,
                    const float* __restrict__ W_fc, // [6,100]
                    const float* __restrict__ b_fc, // [6]
                    float* __restrict__ out)        // [B,NC]
{
    const int b    = blockIdx.x;
    const int tid  = threadIdx.x;
    const int lane = tid & 63;

    __shared__ float h1buf[2][128];   // double-buffered h1_t, padded + zeroed
    __shared__ float h2b[128];
    __shared__ float p[2][448];

    if (tid < 128) {
        h2b[tid] = (tid < HH) ? h0[b * HH + tid] : 0.0f;
        h1buf[0][tid] = 0.0f;
        h1buf[1][tid] = 0.0f;
    }
    float c_reg = (tid < HH) ? c0[b * HH + tid] : 0.0f;

    const bool comp  = (tid < 896);
    const bool half0 = (tid < 448);
    const int  r     = half0 ? tid : (tid - 448);
    const int  row   = (r < G4) ? r : 0;

    float w[HH], bg = 0.0f;
    {
        const float* wsrc = half0 ? (W_ih + row * HH) : (W_hh + row * HH);
        #pragma unroll
        for (int j = 0; j < HH; ++j) w[j] = wsrc[j];
        if (half0) bg = bias_g[row];
    }
    #pragma unroll
    for (int j = 0; j < HH; ++j) asm volatile("" : "+v"(w[j]));  // no remat

    const float* h1b = h1 + (size_t)b * TT * HH;
    __syncthreads();   // pads zeroed before any stage/read

    // prologue: wave 14 stages h1 at t=0
    if (tid >= 896) {
        int i = tid - 896;
        if (i < HH / 4)
            ((float4*)h1buf[0])[i] = ((const float4*)h1b)[i];
    }
    __syncthreads();

    for (int t = 0; t < TT; ++t) {
        const int cur = t & 1;
        if (comp) {
            const float* hsrc = half0 ? h1buf[cur] : h2b;   // wave-uniform
            float va = hsrc[lane];
            float vb = hsrc[64 + lane];   // lanes 0..35 -> h[64..99]; rest pad
            asm volatile("" : "+v"(va), "+v"(vb));
            float a0 = bg, a1 = 0.f;
            #pragma unroll
            for (int j = 0; j < 64; ++j) {
                float h_ = bcast(va, j);
                if (j & 1) a1 += h_ * w[j]; else a0 += h_ * w[j];
            }
            #pragma unroll
            for (int j = 0; j < 36; ++j) {
                float h_ = bcast(vb, j);
                if (j & 1) a1 += h_ * w[64 + j]; else a0 += h_ * w[64 + j];
            }
            p[half0 ? 0 : 1][r] = a0 + a1;
        } else if ((t + 1) < TT) {
            // wave 14: prefetch next h1_t; latency hides under compute phase
            int i = tid - 896;
            if (i < HH / 4)
                ((float4*)h1buf[cur ^ 1])[i] =
                    ((const float4*)(h1b + (t + 1) * HH))[i];
        }
        __syncthreads();
        if (tid < HH) {
            float ri = p[0][tid]          + p[1][tid];
            float rf = p[0][tid + HH]     + p[1][tid + HH];
            float rg = p[0][tid + 2 * HH] + p[1][tid + 2 * HH];
            float ro = p[0][tid + 3 * HH] + p[1][tid + 3 * HH];
            float cc = sigm(rf) * c_reg + sigm(ri) * tanh_fast(rg);
            c_reg = cc;
            h2b[tid] = sigm(ro) * tanh_fast(cc);
        }
        __syncthreads();
    }

    // final FC on h2 at t = T-1
    if (tid < NCLS) {
        float acc = b_fc[tid];
        #pragma unroll 4
        for (int j = 0; j < HH; ++j) acc += W_fc[tid * HH + j] * h2b[j];
        out[b * NCLS + tid] = acc;
    }
}

extern "C" void kernel_launch(void* const* d_in, const int* in_sizes, int n_in,
                              void* d_out, int out_size, void* d_ws, size_t ws_size,
                              hipStream_t stream) {
    const float* x     = (const float*)d_in[0];
    const float* h0_1  = (const float*)d_in[1];
    const float* c0_1  = (const float*)d_in[2];
    const float* h0_2  = (const float*)d_in[3];
    const float* c0_2  = (const float*)d_in[4];
    const float* W_ih1 = (const float*)d_in[5];
    const float* W_hh1 = (const float*)d_in[6];
    const float* b1    = (const float*)d_in[7];
    const float* W_ih2 = (const float*)d_in[8];
    const float* W_hh2 = (const float*)d_in[9];
    const float* b2    = (const float*)d_in[10];
    const float* W_fc  = (const float*)d_in[11];
    const float* b_fc  = (const float*)d_in[12];
    float* out = (float*)d_out;

    float* h1 = (float*)d_ws;   // [B,T,H] fp32 = 104.8 MB

    lstm_layer1<<<BB, 896, 0, stream>>>(x, h0_1, c0_1, W_ih1, W_hh1, b1, h1);
    lstm_layer2_fc<<<BB, 960, 0, stream>>>(h1, h0_2, c0_2, W_ih2, W_hh2, b2,
                                           W_fc, b_fc, out);
}